// Round 1
// baseline (1695.338 us; speedup 1.0000x reference)
//
#include <hip/hip_runtime.h>
#include <math.h>

// GGNN binary classifier: s=4096, N=4 nodes, 8 GRU steps, MLP head.
// Memory-bound on weight streaming: W_ih (402MB) + W_hh (201MB) per step x8,
// + fc1_w (268MB) once => ~5.1 GB fp32 => ~810us roofline at 6.3 TB/s.
//
// This version fuses the a = [A_out@h, A_in@h] computation into the GRU GEMV:
// one 64B h-load feeds 9 W-loads (Wih half1 via A_out, Wih half2 via A_in, Whh
// directly), cutting hot-loop load instructions 84 -> 52 per thread and
// removing 8 compute_a launches + the a_t global round-trip.
//
// Workspace layout:
//   hA, hB: f4[4096], h[k] = {h[0][k], h[1][k], h[2][k], h[3][k]}  (ping-pong)
//   enc:    float[16384]  (h.reshape(1,-1): enc[n*4096+k])
//   x1:     float[4096]

#define S 4096

typedef float f4 __attribute__((ext_vector_type(4)));

__device__ __forceinline__ float wave_reduce_add(float v) {
#pragma unroll
    for (int off = 32; off > 0; off >>= 1) v += __shfl_down(v, off, 64);
    return v;
}

// r[n] = sum_m A[n*4+m] * h[m];  A is wave-uniform (SGPRs)
__device__ __forceinline__ f4 mv4(const float* A, f4 h) {
    f4 r;
    r.x = A[0]  * h.x + A[1]  * h.y + A[2]  * h.z + A[3]  * h.w;
    r.y = A[4]  * h.x + A[5]  * h.y + A[6]  * h.z + A[7]  * h.w;
    r.z = A[8]  * h.x + A[9]  * h.y + A[10] * h.z + A[11] * h.w;
    r.w = A[12] * h.x + A[13] * h.y + A[14] * h.z + A[15] * h.w;
    return r;
}

// acc[n] += dot(w, {v0[n], v1[n], v2[n], v3[n]})
__device__ __forceinline__ void acc4(float* acc, f4 w, f4 v0, f4 v1, f4 v2, f4 v3) {
    acc[0] += w.x * v0.x + w.y * v1.x + w.z * v2.x + w.w * v3.x;
    acc[1] += w.x * v0.y + w.y * v1.y + w.z * v2.y + w.w * v3.y;
    acc[2] += w.x * v0.z + w.y * v1.z + w.z * v2.z + w.w * v3.z;
    acc[3] += w.x * v0.w + w.y * v1.w + w.z * v2.w + w.w * v3.w;
}

__global__ void init_h_k(const float* __restrict__ ann, f4* __restrict__ h) {
    int k = blockIdx.x * 256 + threadIdx.x;  // 0..4095
    f4 o;
    o.x = ann[k];
    o.y = ann[S + k];
    o.z = ann[2 * S + k];
    o.w = ann[3 * S + k];
    h[k] = o;
}

// One block per output column c in [0,4096). Streams rows c, S+c, 2S+c of
// W_ih (K=8192, two halves) and W_hh (K=4096); recomputes a on the fly from
// h and the 4x4 adjacency matrices (uniform, SGPR-resident); applies the GRU
// cell and writes hnext[c].
__global__ __launch_bounds__(256) void gru_fused_k(
    const float* __restrict__ Wih, const float* __restrict__ Whh,
    const float* __restrict__ Aout, const float* __restrict__ Ain,
    const f4* __restrict__ hcur, f4* __restrict__ hnext) {
    const int c = blockIdx.x;
    const int t = threadIdx.x;

    float AO[16], AI[16];
#pragma unroll
    for (int q = 0; q < 16; q++) { AO[q] = Aout[q]; AI[q] = Ain[q]; }

    float accI[3][4];
    float accH[3][4];
#pragma unroll
    for (int g = 0; g < 3; g++)
#pragma unroll
        for (int n = 0; n < 4; n++) { accI[g][n] = 0.f; accH[g][n] = 0.f; }

    const f4* wi0 = (const f4*)(Wih + (size_t)(0 * S + c) * (2 * S));
    const f4* wi1 = (const f4*)(Wih + (size_t)(1 * S + c) * (2 * S));
    const f4* wi2 = (const f4*)(Wih + (size_t)(2 * S + c) * (2 * S));
    const f4* wh0 = (const f4*)(Whh + (size_t)(0 * S + c) * S);
    const f4* wh1 = (const f4*)(Whh + (size_t)(1 * S + c) * S);
    const f4* wh2 = (const f4*)(Whh + (size_t)(2 * S + c) * S);

#pragma unroll 2
    for (int i = 0; i < 4; i++) {
        int j = t + 256 * i;          // float4 index within a 4096-float row
        int kh = 4 * j;               // f4 index into h
        f4 h0 = hcur[kh + 0];
        f4 h1 = hcur[kh + 1];
        f4 h2 = hcur[kh + 2];
        f4 h3 = hcur[kh + 3];

        f4 wA0 = wi0[j];
        f4 wA1 = wi1[j];
        f4 wA2 = wi2[j];
        f4 wB0 = wi0[j + 1024];
        f4 wB1 = wi1[j + 1024];
        f4 wB2 = wi2[j + 1024];
        f4 wC0 = wh0[j];
        f4 wC1 = wh1[j];
        f4 wC2 = wh2[j];

        // a_out = A_out @ h at k = 4j..4j+3  (feeds W_ih first half)
        f4 a0 = mv4(AO, h0);
        f4 a1 = mv4(AO, h1);
        f4 a2 = mv4(AO, h2);
        f4 a3 = mv4(AO, h3);
        acc4(accI[0], wA0, a0, a1, a2, a3);
        acc4(accI[1], wA1, a0, a1, a2, a3);
        acc4(accI[2], wA2, a0, a1, a2, a3);

        // a_in = A_in @ h at the same k  (feeds W_ih second half, offset +4096)
        a0 = mv4(AI, h0);
        a1 = mv4(AI, h1);
        a2 = mv4(AI, h2);
        a3 = mv4(AI, h3);
        acc4(accI[0], wB0, a0, a1, a2, a3);
        acc4(accI[1], wB1, a0, a1, a2, a3);
        acc4(accI[2], wB2, a0, a1, a2, a3);

        // W_hh consumes h directly
        acc4(accH[0], wC0, h0, h1, h2, h3);
        acc4(accH[1], wC1, h0, h1, h2, h3);
        acc4(accH[2], wC2, h0, h1, h2, h3);
    }

    // Block reduction of 24 partials
    __shared__ float red[4][24];
    int lane = t & 63, wid = t >> 6;
#pragma unroll
    for (int g = 0; g < 3; g++) {
#pragma unroll
        for (int n = 0; n < 4; n++) {
            float vI = wave_reduce_add(accI[g][n]);
            float vH = wave_reduce_add(accH[g][n]);
            if (lane == 0) {
                red[wid][g * 4 + n] = vI;
                red[wid][12 + g * 4 + n] = vH;
            }
        }
    }
    __syncthreads();

    if (t < 4) {
        int n = t;
        float I[3], H[3];
#pragma unroll
        for (int g = 0; g < 3; g++) {
            I[g] = red[0][g * 4 + n] + red[1][g * 4 + n] + red[2][g * 4 + n] + red[3][g * 4 + n];
            H[g] = red[0][12 + g * 4 + n] + red[1][12 + g * 4 + n] + red[2][12 + g * 4 + n] + red[3][12 + g * 4 + n];
        }
        float r = 1.f / (1.f + expf(-(I[0] + H[0])));
        float z = 1.f / (1.f + expf(-(I[1] + H[1])));
        float nn = tanhf(I[2] + r * H[2]);
        float hv = ((const float*)hcur)[c * 4 + n];
        ((float*)hnext)[c * 4 + n] = (1.f - z) * nn + z * hv;
    }
}

__global__ void enc_k(const f4* __restrict__ h, float* __restrict__ enc) {
    int idx = blockIdx.x * 256 + threadIdx.x;  // 0..16383
    int n = idx >> 12;
    int k = idx & (S - 1);
    enc[idx] = ((const float*)h)[k * 4 + n];
}

__global__ __launch_bounds__(256) void fc1_k(const float* __restrict__ W, const float* __restrict__ b,
                                             const float* __restrict__ enc, float* __restrict__ x1) {
    int j = blockIdx.x, t = threadIdx.x;
    const f4* row = (const f4*)(W + (size_t)j * (4 * S));
    const f4* e4 = (const f4*)enc;
    float acc = 0.f;
#pragma unroll 4
    for (int i = 0; i < 16; i++) {
        int m = t + 256 * i;  // 0..4095 f4 idx
        f4 w = row[m];
        f4 e = e4[m];
        acc += w.x * e.x + w.y * e.y + w.z * e.z + w.w * e.w;
    }
    acc = wave_reduce_add(acc);
    __shared__ float red[4];
    if ((t & 63) == 0) red[t >> 6] = acc;
    __syncthreads();
    if (t == 0) x1[j] = red[0] + red[1] + red[2] + red[3] + b[j];
}

__global__ __launch_bounds__(256) void fc2_k(const float* __restrict__ W, const float* __restrict__ b,
                                             const float* __restrict__ x1, float* __restrict__ out) {
    int t = threadIdx.x;
    const f4* x4 = (const f4*)x1;
    const f4* w0 = (const f4*)W;
    const f4* w1 = (const f4*)(W + S);
    float a0 = 0.f, a1 = 0.f;
#pragma unroll
    for (int i = 0; i < 4; i++) {
        int m = t + 256 * i;  // 0..1023
        f4 x = x4[m];
        f4 u = w0[m];
        f4 v = w1[m];
        a0 += u.x * x.x + u.y * x.y + u.z * x.z + u.w * x.w;
        a1 += v.x * x.x + v.y * x.y + v.z * x.z + v.w * x.w;
    }
    a0 = wave_reduce_add(a0);
    a1 = wave_reduce_add(a1);
    __shared__ float red0[4], red1[4];
    int lane = t & 63, wid = t >> 6;
    if (lane == 0) { red0[wid] = a0; red1[wid] = a1; }
    __syncthreads();
    if (t == 0) {
        float l0 = red0[0] + red0[1] + red0[2] + red0[3] + b[0];
        float l1 = red1[0] + red1[1] + red1[2] + red1[3] + b[1];
        float m = fmaxf(l0, l1);
        float ls = m + logf(expf(l0 - m) + expf(l1 - m));
        out[0] = l0 - ls;
        out[1] = l1 - ls;
    }
}

extern "C" void kernel_launch(void* const* d_in, const int* in_sizes, int n_in,
                              void* d_out, int out_size, void* d_ws, size_t ws_size,
                              hipStream_t stream) {
    const float* A_out = (const float*)d_in[0];
    const float* A_in  = (const float*)d_in[1];
    const float* ann   = (const float*)d_in[2];
    const float* W_ih  = (const float*)d_in[3];
    const float* W_hh  = (const float*)d_in[4];
    const float* fc1_w = (const float*)d_in[5];
    const float* fc1_b = (const float*)d_in[6];
    const float* fc2_w = (const float*)d_in[7];
    const float* fc2_b = (const float*)d_in[8];
    float* out = (float*)d_out;

    float* ws_f = (float*)d_ws;
    f4* hA  = (f4*)ws_f;                  // 4096 f4
    f4* hB  = hA + S;                     // 4096 f4
    float* enc = (float*)(hB + S);        // 16384 floats
    float* x1  = enc + 4 * S;             // 4096 floats

    init_h_k<<<S / 256, 256, 0, stream>>>(ann, hA);

    for (int step = 0; step < 8; step++) {
        f4* cur = (step & 1) ? hB : hA;
        f4* nxt = (step & 1) ? hA : hB;
        gru_fused_k<<<S, 256, 0, stream>>>(W_ih, W_hh, A_out, A_in, cur, nxt);
    }
    // After 8 steps the final state is back in hA.
    enc_k<<<4 * S / 256, 256, 0, stream>>>(hA, enc);
    fc1_k<<<S, 256, 0, stream>>>(fc1_w, fc1_b, enc, x1);
    fc2_k<<<1, 256, 0, stream>>>(fc2_w, fc2_b, x1, out);
}